// Round 12
// baseline (259.810 us; speedup 1.0000x reference)
//
#include <hip/hip_runtime.h>

#define N_NODES 50000
#define N_EDGES 800000
#define CDIM 100
#define HDIM 200
#define ODIM 100

#define PITCH_U 64   // node rows: 128 bf16 = 64 uints = 256 B

typedef __bf16 bf16x8 __attribute__((ext_vector_type(8)));
typedef float f32x4 __attribute__((ext_vector_type(4)));
typedef unsigned short ushort_t;

__device__ __forceinline__ unsigned f2bf(float f) {
    unsigned u = __float_as_uint(f);
    u = (u + 0x7FFFu + ((u >> 16) & 1u)) >> 16;
    return u;  // low 16 bits valid
}
__device__ __forceinline__ float bflo(unsigned u) { return __uint_as_float(u << 16); }
__device__ __forceinline__ float bfhi(unsigned u) { return __uint_as_float(u & 0xFFFF0000u); }

// ---- CSR aggregation core: returns per-lane (col 2*lane, 2*lane+1) fp32 sums ----
__device__ __forceinline__ float2 agg_core(int n, int lane, const unsigned* __restrict__ hb,
                                           const int* __restrict__ ssrc,
                                           const int* __restrict__ off) {
    int s0 = off[n], s1 = off[n + 1];
    float2 a0 = {0.f, 0.f}, a1 = {0.f, 0.f}, a2 = {0.f, 0.f}, a3 = {0.f, 0.f};
    int j = s0;
    for (; j + 7 < s1; j += 8) {
        int r0 = ssrc[j],     r1 = ssrc[j + 1], r2 = ssrc[j + 2], r3 = ssrc[j + 3];
        int r4 = ssrc[j + 4], r5 = ssrc[j + 5], r6 = ssrc[j + 6], r7 = ssrc[j + 7];
        unsigned u0 = hb[(size_t)r0 * PITCH_U + lane];
        unsigned u1 = hb[(size_t)r1 * PITCH_U + lane];
        unsigned u2 = hb[(size_t)r2 * PITCH_U + lane];
        unsigned u3 = hb[(size_t)r3 * PITCH_U + lane];
        unsigned u4 = hb[(size_t)r4 * PITCH_U + lane];
        unsigned u5 = hb[(size_t)r5 * PITCH_U + lane];
        unsigned u6 = hb[(size_t)r6 * PITCH_U + lane];
        unsigned u7 = hb[(size_t)r7 * PITCH_U + lane];
        a0.x += bflo(u0); a0.y += bfhi(u0);
        a1.x += bflo(u1); a1.y += bfhi(u1);
        a2.x += bflo(u2); a2.y += bfhi(u2);
        a3.x += bflo(u3); a3.y += bfhi(u3);
        a0.x += bflo(u4); a0.y += bfhi(u4);
        a1.x += bflo(u5); a1.y += bfhi(u5);
        a2.x += bflo(u6); a2.y += bfhi(u6);
        a3.x += bflo(u7); a3.y += bfhi(u7);
    }
    for (; j + 3 < s1; j += 4) {
        int r0 = ssrc[j], r1 = ssrc[j + 1], r2 = ssrc[j + 2], r3 = ssrc[j + 3];
        unsigned u0 = hb[(size_t)r0 * PITCH_U + lane];
        unsigned u1 = hb[(size_t)r1 * PITCH_U + lane];
        unsigned u2 = hb[(size_t)r2 * PITCH_U + lane];
        unsigned u3 = hb[(size_t)r3 * PITCH_U + lane];
        a0.x += bflo(u0); a0.y += bfhi(u0);
        a1.x += bflo(u1); a1.y += bfhi(u1);
        a2.x += bflo(u2); a2.y += bfhi(u2);
        a3.x += bflo(u3); a3.y += bfhi(u3);
    }
    {
        int rem = s1 - j;
        if (rem > 0) { unsigned u = hb[(size_t)ssrc[j] * PITCH_U + lane];     a0.x += bflo(u); a0.y += bfhi(u); }
        if (rem > 1) { unsigned u = hb[(size_t)ssrc[j + 1] * PITCH_U + lane]; a1.x += bflo(u); a1.y += bfhi(u); }
        if (rem > 2) { unsigned u = hb[(size_t)ssrc[j + 2] * PITCH_U + lane]; a2.x += bflo(u); a2.y += bfhi(u); }
    }
    return make_float2((a0.x + a1.x) + (a2.x + a3.x), (a0.y + a1.y) + (a2.y + a3.y));
}

// ---------------- CSR build ----------------

__global__ void count_rank(const int* __restrict__ dst, int* __restrict__ deg,
                           int* __restrict__ rank) {
    int e = blockIdx.x * 256 + threadIdx.x;
    if (e < N_EDGES) rank[e] = atomicAdd(&deg[dst[e]], 1);
}

__global__ __launch_bounds__(1024) void scan_deg(const int* __restrict__ deg,
                                                 int* __restrict__ off) {
    const int T = 1024;
    const int PER = 52;  // 13 int4s; 962 threads cover 50000
    int t = threadIdx.x;
    int start = t * PER;
    const int4* deg4 = (const int4*)deg;

    int sum = 0;
    if (start + PER <= N_NODES) {
#pragma unroll
        for (int q = 0; q < PER / 4; ++q) {
            int4 v = deg4[start / 4 + q];
            sum += v.x + v.y + v.z + v.w;
        }
    } else {
        for (int i = start; i < N_NODES; ++i) sum += deg[i];
    }

    __shared__ int ls[T];
    ls[t] = sum;
    __syncthreads();
    for (int o = 1; o < T; o <<= 1) {
        int v = (t >= o) ? ls[t - o] : 0;
        __syncthreads();
        ls[t] += v;
        __syncthreads();
    }
    int run = (t == 0) ? 0 : ls[t - 1];

    if (start + PER <= N_NODES) {
        int4* off4 = (int4*)off;
#pragma unroll
        for (int q = 0; q < PER / 4; ++q) {
            int4 v = deg4[start / 4 + q];
            int4 o;
            o.x = run;
            o.y = o.x + v.x;
            o.z = o.y + v.y;
            o.w = o.z + v.z;
            run = o.w + v.w;
            off4[start / 4 + q] = o;
        }
    } else if (start <= N_NODES) {
        for (int i = start; i < N_NODES; ++i) {
            off[i] = run;
            run += deg[i];
        }
        off[N_NODES] = run;
    }
}

// ---------------- fused independent stage: scatter | gather | weight-prep ----------

__global__ __launch_bounds__(256) void scatter_gather_prep(
    const int* __restrict__ esrc, const int* __restrict__ edst,
    const int* __restrict__ off, const int* __restrict__ rank, int* __restrict__ ssrc,
    const float4* __restrict__ emb, const int* __restrict__ ids, uint2* __restrict__ h0,
    const float* __restrict__ W1, const float* __restrict__ W2,
    ushort_t* __restrict__ W1t, ushort_t* __restrict__ W2t) {
    int b = blockIdx.x;
    if (b < 3125) {
        int e = b * 256 + threadIdx.x;
        if (e < N_EDGES) {
            int p = off[edst[e]] + rank[e];   // off: 200KB, L2-resident -> cheap gather
            ssrc[p] = esrc[e];
        }
    } else if (b < 9375) {
        int i = (b - 3125) * 256 + threadIdx.x;  // i = n*32+q (32 uint2 per row)
        const int TOT = N_NODES * 32;            // 1.6M uint2
        if (i < TOT) {
            int n = i >> 5, q = i & 31;
            uint2 o = make_uint2(0u, 0u);
            if (q < 25) {
                float4 v = emb[(size_t)ids[n] * 25 + q];
                o.x = f2bf(v.x) | (f2bf(v.y) << 16);
                o.y = f2bf(v.z) | (f2bf(v.w) << 16);
            }
            h0[i] = o;
        }
    } else {
        int i = (b - 9375) * 256 + threadIdx.x;
        if (i < 208 * 128) {
            int n = i >> 7, k = i & 127;
            float v = (n < HDIM && k < CDIM) ? W1[k * HDIM + n] : 0.f;
            W1t[i] = (ushort_t)f2bf(v);
        } else {
            int j = i - 208 * 128;
            if (j < 112 * 256) {
                int n = j >> 8, k = j & 255;
                float v = (n < ODIM && k < HDIM) ? W2[k * ODIM + n] : 0.f;
                W2t[j] = (ushort_t)f2bf(v);
            }
        }
    }
}

// ---------------- fused agg1 + MLP: g = relu(segsum(h0)@W1+b1)@W2, per 64-node tile ----
// Phase A: wave w aggregates local nodes w*16..w*16+15 into LDS As[64][136 bf16].
// Phase B: A-frags -> regs, barrier (LDS re-used as H1s[64][264]), two MFMA stages.
// g out: pitch-256B rows, pad cols zeroed.

__global__ __launch_bounds__(256) void agg_mlp(const unsigned* __restrict__ hb,
                                               const int* __restrict__ ssrc,
                                               const int* __restrict__ off,
                                               const ushort_t* __restrict__ W1t,
                                               const float* __restrict__ b1,
                                               const ushort_t* __restrict__ W2t,
                                               ushort_t* __restrict__ gb) {
    const int P2 = 264;   // H1s pitch (bf16)
    const int AP = 136;   // As pitch (bf16) = 68 uints: breaks pow2 banks, keeps 16B align
    __shared__ alignas(16) ushort_t smem[64 * P2];  // 33.8 KB (As phase uses first 17.4 KB)
    unsigned* AsU = (unsigned*)smem;                // [64][68] uints
    ushort_t* As = smem;                            // bf16 view, pitch 136
    ushort_t* H1s = smem;                           // [64][264] bf16 (after barrier)

    int tid = threadIdx.x, lane = tid & 63, w = tid >> 6;
    int rl = lane & 15, kg = lane >> 4;
    int row0 = blockIdx.x * 64;

    // ---- Phase A: aggregate 16 nodes per wave into As ----
#pragma unroll 1
    for (int i = 0; i < 16; ++i) {
        int l = w * 16 + i;
        int n = row0 + l;
        if (n < N_NODES) {
            float2 r = agg_core(n, lane, hb, ssrc, off);
            AsU[l * (AP / 2) + lane] = f2bf(r.x) | (f2bf(r.y) << 16);
        }
    }
    __syncthreads();

    // ---- Phase B1: A fragments -> registers ----
    bf16x8 afr[4];
#pragma unroll
    for (int k2 = 0; k2 < 4; ++k2)
        afr[k2] = *reinterpret_cast<const bf16x8*>(&As[(w * 16 + rl) * AP + k2 * 32 + kg * 8]);
    __syncthreads();  // all As reads done; smem becomes H1s

    // zero H1s pad cols 200..263
    for (int idx = tid; idx < 64 * 32; idx += 256) {
        int r = idx >> 5, c = idx & 31;
        ((unsigned*)&H1s[r * P2 + 200])[c] = 0;
    }

    // ---- stage 1: h1 = relu(A @ W1t^T + b1) -> H1s ----
    f32x4 acc1[13];
#pragma unroll
    for (int t = 0; t < 13; ++t) acc1[t] = (f32x4){0.f, 0.f, 0.f, 0.f};
#pragma unroll
    for (int k2 = 0; k2 < 4; ++k2) {
#pragma unroll
        for (int t = 0; t < 13; ++t) {
            bf16x8 b = *reinterpret_cast<const bf16x8*>(&W1t[(t * 16 + rl) * 128 + k2 * 32 + kg * 8]);
            acc1[t] = __builtin_amdgcn_mfma_f32_16x16x32_bf16(afr[k2], b, acc1[t], 0, 0, 0);
        }
    }
#pragma unroll
    for (int t = 0; t < 13; ++t) {
        int col = t * 16 + rl;
        if (col < HDIM) {
            float bv = b1[col];
#pragma unroll
            for (int i = 0; i < 4; ++i) {
                int r = w * 16 + kg * 4 + i;
                H1s[r * P2 + col] = (ushort_t)f2bf(fmaxf(acc1[t][i] + bv, 0.f));
            }
        }
    }
    __syncthreads();

    // ---- stage 2: g = h1 @ W2t^T ----
    f32x4 acc2[7];
#pragma unroll
    for (int t = 0; t < 7; ++t) acc2[t] = (f32x4){0.f, 0.f, 0.f, 0.f};
#pragma unroll
    for (int k2 = 0; k2 < 8; ++k2) {
        bf16x8 a = *reinterpret_cast<const bf16x8*>(&H1s[(w * 16 + rl) * P2 + k2 * 32 + kg * 8]);
#pragma unroll
        for (int t = 0; t < 7; ++t) {
            bf16x8 b = *reinterpret_cast<const bf16x8*>(&W2t[(t * 16 + rl) * 256 + k2 * 32 + kg * 8]);
            acc2[t] = __builtin_amdgcn_mfma_f32_16x16x32_bf16(a, b, acc2[t], 0, 0, 0);
        }
    }

    // epilogue: D layout col=lane&15, row=(lane>>4)*4+i  [m89]
#pragma unroll
    for (int t = 0; t < 7; ++t) {
        int col = t * 16 + rl;
#pragma unroll
        for (int i = 0; i < 4; ++i) {
            int row = row0 + w * 16 + kg * 4 + i;
            if (row < N_NODES) {
                float v = (col < ODIM) ? acc2[t][i] : 0.f;
                gb[(size_t)row * 128 + col] = (ushort_t)f2bf(v);
            }
        }
    }
    unsigned* gbu = (unsigned*)gb;
    for (int idx = tid; idx < 64 * 8; idx += 256) {
        int r = idx >> 3, c = idx & 7;
        int row = row0 + r;
        if (row < N_NODES) gbu[(size_t)row * PITCH_U + 56 + c] = 0;
    }
}

// ---------------- final aggregation: out = relu(segsum(g[src]) + b2) ----------------

__global__ __launch_bounds__(256) void agg_out(const unsigned* __restrict__ hb,
                                               const int* __restrict__ ssrc,
                                               const int* __restrict__ off,
                                               const float* __restrict__ bias,
                                               float2* __restrict__ outf) {
    int wave = threadIdx.x >> 6;
    int lane = threadIdx.x & 63;
    int n = blockIdx.x * 4 + wave;
    if (n >= N_NODES) return;
    float2 r = agg_core(n, lane, hb, ssrc, off);
    if (lane < 50) {
        float rx = fmaxf(r.x + bias[2 * lane], 0.f);
        float ry = fmaxf(r.y + bias[2 * lane + 1], 0.f);
        outf[(size_t)n * 50 + lane] = make_float2(rx, ry);
    }
}

// ---------------- launch ----------------

extern "C" void kernel_launch(void* const* d_in, const int* in_sizes, int n_in,
                              void* d_out, int out_size, void* d_ws, size_t ws_size,
                              hipStream_t stream) {
    const float4* emb = (const float4*)d_in[0];
    const float* W1  = (const float*)d_in[1];
    const float* b1  = (const float*)d_in[2];
    const float* W2  = (const float*)d_in[3];
    const float* b2  = (const float*)d_in[4];
    const int* ids   = (const int*)d_in[5];
    const int* esrc  = (const int*)d_in[6];
    const int* edst  = (const int*)d_in[7];
    float2* out = (float2*)d_out;

    // workspace layout (~33 MB)
    unsigned* h0b = (unsigned*)d_ws;                    // [N][64] uints (bf16 pairs)
    unsigned* gbu = h0b + (size_t)N_NODES * PITCH_U;    // [N][64] uints
    ushort_t* W1t = (ushort_t*)(gbu + (size_t)N_NODES * PITCH_U);  // [208][128]
    ushort_t* W2t = W1t + 208 * 128;                    // [112][256]
    int* deg   = (int*)(W2t + 112 * 256);
    int* off   = deg + N_NODES;                         // N+1
    int* rank  = off + (N_NODES + 1);                   // 800K
    int* ssrc  = rank + N_EDGES;                        // 800K

    hipMemsetAsync(deg, 0, N_NODES * sizeof(int), stream);

    // CSR build: one atomic pass (deg + rank), scan, then atomic-free scatter
    count_rank<<<(N_EDGES + 255) / 256, 256, 0, stream>>>(edst, deg, rank);
    scan_deg<<<1, 1024, 0, stream>>>(deg, off);

    // scatter + h0 gather + weight-prep (mutually independent) in one launch
    scatter_gather_prep<<<9591, 256, 0, stream>>>(esrc, edst, off, rank, ssrc,
                                                  emb, ids, (uint2*)h0b,
                                                  W1, W2, W1t, W2t);

    // agg1 + MLP fused: g = relu(segsum(h0)@W1+b1)@W2  (agg tile never leaves LDS)
    agg_mlp<<<(N_NODES + 63) / 64, 256, 0, stream>>>(h0b, ssrc, off, W1t, b1, W2t,
                                                     (ushort_t*)gbu);
    // out = relu(segsum(g[src]) + b2)  (fp32 out)
    agg_out<<<N_NODES / 4, 256, 0, stream>>>(gbu, ssrc, off, b2, out);
}

// Round 13
// 204.953 us; speedup vs baseline: 1.2677x; 1.2677x over previous
//
#include <hip/hip_runtime.h>

#define N_NODES 50000
#define N_EDGES 800000
#define CDIM 100
#define HDIM 200
#define ODIM 100

#define PITCH_U 64   // node rows: 128 bf16 = 64 uints = 256 B
#define PITCH_U2 32  // same, in uint2

typedef __bf16 bf16x8 __attribute__((ext_vector_type(8)));
typedef float f32x4 __attribute__((ext_vector_type(4)));
typedef unsigned short ushort_t;

__device__ __forceinline__ unsigned f2bf(float f) {
    unsigned u = __float_as_uint(f);
    u = (u + 0x7FFFu + ((u >> 16) & 1u)) >> 16;
    return u;  // low 16 bits valid
}
__device__ __forceinline__ float bflo(unsigned u) { return __uint_as_float(u << 16); }
__device__ __forceinline__ float bfhi(unsigned u) { return __uint_as_float(u & 0xFFFF0000u); }

#define ACC4(a, u)                          \
    do {                                    \
        (a).x += bflo((u).x);               \
        (a).y += bfhi((u).x);               \
        (a).z += bflo((u).y);               \
        (a).w += bfhi((u).y);               \
    } while (0)

// ---- CSR aggregation core, 2 edges per wave-load ----
// lanes 0..31 handle even-parity edges, lanes 32..63 odd-parity; each lane owns
// cols 4*li..4*li+3 (li = lane&31). Cross-half combine via shfl_xor(32) at the end.
// Returns the full-row sums (all lanes hold cols 4*li..4*li+3).

__device__ __forceinline__ float4 agg_core2(int n, int lane, const uint2* __restrict__ hb2,
                                            const int* __restrict__ ssrc,
                                            const int* __restrict__ off) {
    int s0 = off[n], s1 = off[n + 1];
    int half = lane >> 5;
    int li = lane & 31;
    float4 a0 = {0.f, 0.f, 0.f, 0.f}, a1 = {0.f, 0.f, 0.f, 0.f};
    float4 a2 = {0.f, 0.f, 0.f, 0.f}, a3 = {0.f, 0.f, 0.f, 0.f};
    int j = s0;
    for (; j + 7 < s1; j += 8) {  // 8 edges = 4 dual-row loads in flight
        int i0 = ssrc[j + 0 + half];
        int i1 = ssrc[j + 2 + half];
        int i2 = ssrc[j + 4 + half];
        int i3 = ssrc[j + 6 + half];
        uint2 u0 = hb2[(size_t)i0 * PITCH_U2 + li];
        uint2 u1 = hb2[(size_t)i1 * PITCH_U2 + li];
        uint2 u2 = hb2[(size_t)i2 * PITCH_U2 + li];
        uint2 u3 = hb2[(size_t)i3 * PITCH_U2 + li];
        ACC4(a0, u0);
        ACC4(a1, u1);
        ACC4(a2, u2);
        ACC4(a3, u3);
    }
    {   // pair tail: up to 3 independent dual-row loads (wave-uniform guards)
        int p = (s1 - j) >> 1;
        if (p > 0) { int i = ssrc[j + 0 + half]; uint2 u = hb2[(size_t)i * PITCH_U2 + li]; ACC4(a0, u); }
        if (p > 1) { int i = ssrc[j + 2 + half]; uint2 u = hb2[(size_t)i * PITCH_U2 + li]; ACC4(a1, u); }
        if (p > 2) { int i = ssrc[j + 4 + half]; uint2 u = hb2[(size_t)i * PITCH_U2 + li]; ACC4(a2, u); }
        j += 2 * p;
    }
    if (j < s1) {  // odd edge: both halves load it, only half 0 accumulates
        int i = ssrc[j];
        uint2 u = hb2[(size_t)i * PITCH_U2 + li];
        if (half == 0) ACC4(a3, u);
    }
    float4 s;
    s.x = (a0.x + a1.x) + (a2.x + a3.x);
    s.y = (a0.y + a1.y) + (a2.y + a3.y);
    s.z = (a0.z + a1.z) + (a2.z + a3.z);
    s.w = (a0.w + a1.w) + (a2.w + a3.w);
    s.x += __shfl_xor(s.x, 32);
    s.y += __shfl_xor(s.y, 32);
    s.z += __shfl_xor(s.z, 32);
    s.w += __shfl_xor(s.w, 32);
    return s;
}

// ---------------- fused independent stage: count_rank | gather | weight-prep ----------
// blocks [0,3125): deg histogram + per-edge rank (atomics)
// blocks [3125,9375): h0 = bf16(emb[ids]) into pitch-256B rows (pad cols zeroed)
// blocks [9375,9591): W1t[208][128] <- bf16(W1^T); W2t[112][256] <- bf16(W2^T)

__global__ __launch_bounds__(256) void count_gather_prep(
    const int* __restrict__ edst, int* __restrict__ deg, int* __restrict__ rank,
    const float4* __restrict__ emb, const int* __restrict__ ids, uint2* __restrict__ h0,
    const float* __restrict__ W1, const float* __restrict__ W2,
    ushort_t* __restrict__ W1t, ushort_t* __restrict__ W2t) {
    int b = blockIdx.x;
    if (b < 3125) {
        int e = b * 256 + threadIdx.x;  // 3125*256 == N_EDGES
        rank[e] = atomicAdd(&deg[edst[e]], 1);
    } else if (b < 9375) {
        int i = (b - 3125) * 256 + threadIdx.x;  // i = n*32+q (32 uint2 per row)
        int n = i >> 5, q = i & 31;              // 6250*256 == N*32
        uint2 o = make_uint2(0u, 0u);
        if (q < 25) {
            float4 v = emb[(size_t)ids[n] * 25 + q];
            o.x = f2bf(v.x) | (f2bf(v.y) << 16);
            o.y = f2bf(v.z) | (f2bf(v.w) << 16);
        }
        h0[i] = o;
    } else {
        int i = (b - 9375) * 256 + threadIdx.x;
        if (i < 208 * 128) {
            int n = i >> 7, k = i & 127;
            float v = (n < HDIM && k < CDIM) ? W1[k * HDIM + n] : 0.f;
            W1t[i] = (ushort_t)f2bf(v);
        } else {
            int j = i - 208 * 128;
            if (j < 112 * 256) {
                int n = j >> 8, k = j & 255;
                float v = (n < ODIM && k < HDIM) ? W2[k * ODIM + n] : 0.f;
                W2t[j] = (ushort_t)f2bf(v);
            }
        }
    }
}

__global__ __launch_bounds__(1024) void scan_deg(const int* __restrict__ deg,
                                                 int* __restrict__ off) {
    const int T = 1024;
    const int PER = 52;  // 13 int4s; 962 threads cover 50000
    int t = threadIdx.x;
    int start = t * PER;
    const int4* deg4 = (const int4*)deg;

    int sum = 0;
    if (start + PER <= N_NODES) {
#pragma unroll
        for (int q = 0; q < PER / 4; ++q) {
            int4 v = deg4[start / 4 + q];
            sum += v.x + v.y + v.z + v.w;
        }
    } else {
        for (int i = start; i < N_NODES; ++i) sum += deg[i];
    }

    __shared__ int ls[T];
    ls[t] = sum;
    __syncthreads();
    for (int o = 1; o < T; o <<= 1) {
        int v = (t >= o) ? ls[t - o] : 0;
        __syncthreads();
        ls[t] += v;
        __syncthreads();
    }
    int run = (t == 0) ? 0 : ls[t - 1];

    if (start + PER <= N_NODES) {
        int4* off4 = (int4*)off;
#pragma unroll
        for (int q = 0; q < PER / 4; ++q) {
            int4 v = deg4[start / 4 + q];
            int4 o;
            o.x = run;
            o.y = o.x + v.x;
            o.z = o.y + v.y;
            o.w = o.z + v.z;
            run = o.w + v.w;
            off4[start / 4 + q] = o;
        }
    } else if (start <= N_NODES) {
        for (int i = start; i < N_NODES; ++i) {
            off[i] = run;
            run += deg[i];
        }
        off[N_NODES] = run;
    }
}

// ---------------- atomic-free scatter: slot = off[dst] + rank ----------------

__global__ __launch_bounds__(256) void scatter(const int* __restrict__ esrc,
                                               const int* __restrict__ edst,
                                               const int* __restrict__ off,
                                               const int* __restrict__ rank,
                                               int* __restrict__ ssrc) {
    int e = blockIdx.x * 256 + threadIdx.x;
    if (e < N_EDGES) {
        int p = off[edst[e]] + rank[e];
        ssrc[p] = esrc[e];
    }
}

// ---------------- agg1: a1 = segsum(h0[src]) -> bf16 pitch-256B ----------------

__global__ __launch_bounds__(256) void agg1(const uint2* __restrict__ hb2,
                                            const int* __restrict__ ssrc,
                                            const int* __restrict__ off,
                                            uint2* __restrict__ out2) {
    int wave = threadIdx.x >> 6;
    int lane = threadIdx.x & 63;
    int n = blockIdx.x * 4 + wave;
    if (n >= N_NODES) return;
    float4 s = agg_core2(n, lane, hb2, ssrc, off);
    if (lane < 32) {  // 32 lanes cover the 64-uint row
        uint2 o;
        o.x = f2bf(s.x) | (f2bf(s.y) << 16);
        o.y = f2bf(s.z) | (f2bf(s.w) << 16);
        out2[(size_t)n * PITCH_U2 + lane] = o;
    }
}

// ---------------- fused MLP: g = relu(A @ W1t^T + b1) @ W2t^T (R11-proven) --------

__global__ __launch_bounds__(256) void gemm_fused(const ushort_t* __restrict__ Ab,
                                                  const ushort_t* __restrict__ W1t,
                                                  const float* __restrict__ b1,
                                                  const ushort_t* __restrict__ W2t,
                                                  ushort_t* __restrict__ gb) {
    const int P2 = 264;  // H1s row pitch (bf16): 200 data + 56 zero + 8 slack
    __shared__ alignas(16) ushort_t H1s[64 * P2];  // 33.8 KB

    int tid = threadIdx.x, lane = tid & 63, w = tid >> 6;
    int rl = lane & 15, kg = lane >> 4;
    int row0 = blockIdx.x * 64;

    size_t abase = ((size_t)(row0 + w * 16 + rl)) * 128;
    f32x4 acc1[13];
#pragma unroll
    for (int t = 0; t < 13; ++t) acc1[t] = (f32x4){0.f, 0.f, 0.f, 0.f};
#pragma unroll
    for (int k2 = 0; k2 < 4; ++k2) {
        bf16x8 a = *reinterpret_cast<const bf16x8*>(&Ab[abase + k2 * 32 + kg * 8]);
#pragma unroll
        for (int t = 0; t < 13; ++t) {
            bf16x8 b = *reinterpret_cast<const bf16x8*>(&W1t[(t * 16 + rl) * 128 + k2 * 32 + kg * 8]);
            acc1[t] = __builtin_amdgcn_mfma_f32_16x16x32_bf16(a, b, acc1[t], 0, 0, 0);
        }
    }
    // zero pad cols 200..263
    for (int idx = tid; idx < 64 * 32; idx += 256) {
        int r = idx >> 5, c = idx & 31;
        ((unsigned*)&H1s[r * P2 + 200])[c] = 0;
    }
    // h1 = relu(acc1 + b1) -> bf16 LDS tile (D layout: col=lane&15, row=(lane>>4)*4+i)
#pragma unroll
    for (int t = 0; t < 13; ++t) {
        int col = t * 16 + rl;
        if (col < HDIM) {
            float bv = b1[col];
#pragma unroll
            for (int i = 0; i < 4; ++i) {
                int r = w * 16 + kg * 4 + i;
                H1s[r * P2 + col] = (ushort_t)f2bf(fmaxf(acc1[t][i] + bv, 0.f));
            }
        }
    }
    __syncthreads();

    f32x4 acc2[7];
#pragma unroll
    for (int t = 0; t < 7; ++t) acc2[t] = (f32x4){0.f, 0.f, 0.f, 0.f};
#pragma unroll
    for (int k2 = 0; k2 < 8; ++k2) {
        bf16x8 a = *reinterpret_cast<const bf16x8*>(&H1s[(w * 16 + rl) * P2 + k2 * 32 + kg * 8]);
#pragma unroll
        for (int t = 0; t < 7; ++t) {
            bf16x8 b = *reinterpret_cast<const bf16x8*>(&W2t[(t * 16 + rl) * 256 + k2 * 32 + kg * 8]);
            acc2[t] = __builtin_amdgcn_mfma_f32_16x16x32_bf16(a, b, acc2[t], 0, 0, 0);
        }
    }

#pragma unroll
    for (int t = 0; t < 7; ++t) {
        int col = t * 16 + rl;
#pragma unroll
        for (int i = 0; i < 4; ++i) {
            int row = row0 + w * 16 + kg * 4 + i;
            if (row < N_NODES) {
                float v = (col < ODIM) ? acc2[t][i] : 0.f;
                gb[(size_t)row * 128 + col] = (ushort_t)f2bf(v);
            }
        }
    }
    unsigned* gbu = (unsigned*)gb;
    for (int idx = tid; idx < 64 * 8; idx += 256) {
        int r = idx >> 3, c = idx & 7;
        int row = row0 + r;
        if (row < N_NODES) gbu[(size_t)row * PITCH_U + 56 + c] = 0;
    }
}

// ---------------- final aggregation: out = relu(segsum(g[src]) + b2) ----------------

__global__ __launch_bounds__(256) void agg_out(const uint2* __restrict__ hb2,
                                               const int* __restrict__ ssrc,
                                               const int* __restrict__ off,
                                               const float* __restrict__ bias,
                                               float4* __restrict__ outf) {
    int wave = threadIdx.x >> 6;
    int lane = threadIdx.x & 63;
    int n = blockIdx.x * 4 + wave;
    if (n >= N_NODES) return;
    float4 s = agg_core2(n, lane, hb2, ssrc, off);
    if (lane < 25) {  // 25 lanes x float4 = 100 fp32 cols
        float4 bv = ((const float4*)bias)[lane];
        float4 r;
        r.x = fmaxf(s.x + bv.x, 0.f);
        r.y = fmaxf(s.y + bv.y, 0.f);
        r.z = fmaxf(s.z + bv.z, 0.f);
        r.w = fmaxf(s.w + bv.w, 0.f);
        outf[(size_t)n * 25 + lane] = r;
    }
}

// ---------------- launch ----------------

extern "C" void kernel_launch(void* const* d_in, const int* in_sizes, int n_in,
                              void* d_out, int out_size, void* d_ws, size_t ws_size,
                              hipStream_t stream) {
    const float4* emb = (const float4*)d_in[0];
    const float* W1  = (const float*)d_in[1];
    const float* b1  = (const float*)d_in[2];
    const float* W2  = (const float*)d_in[3];
    const float* b2  = (const float*)d_in[4];
    const int* ids   = (const int*)d_in[5];
    const int* esrc  = (const int*)d_in[6];
    const int* edst  = (const int*)d_in[7];
    float4* out = (float4*)d_out;

    // workspace layout (~33 MB)
    unsigned* h0b = (unsigned*)d_ws;                    // [N][64] uints (bf16 pairs)
    unsigned* gbu = h0b + (size_t)N_NODES * PITCH_U;    // [N][64] uints
    ushort_t* W1t = (ushort_t*)(gbu + (size_t)N_NODES * PITCH_U);  // [208][128]
    ushort_t* W2t = W1t + 208 * 128;                    // [112][256]
    int* deg   = (int*)(W2t + 112 * 256);
    int* off   = deg + N_NODES;                         // N+1
    int* rank  = off + (N_NODES + 1);                   // 800K
    int* ssrc  = rank + N_EDGES;                        // 800K

    hipMemsetAsync(deg, 0, N_NODES * sizeof(int), stream);

    // count_rank | h0 gather | weight prep (independent) in one launch
    count_gather_prep<<<9591, 256, 0, stream>>>(edst, deg, rank,
                                                emb, ids, (uint2*)h0b,
                                                W1, W2, W1t, W2t);
    scan_deg<<<1, 1024, 0, stream>>>(deg, off);
    // atomic-free scatter
    scatter<<<3125, 256, 0, stream>>>(esrc, edst, off, rank, ssrc);

    // agg1 = segsum(h0[src])  (bf16 pitch-256B out)
    agg1<<<N_NODES / 4, 256, 0, stream>>>((const uint2*)h0b, ssrc, off, (uint2*)gbu + 0);
    // NOTE: agg1 output goes to a1 region = reuse h0b? NO — h0 still needed? No! h0 is
    // only read by agg1 itself. But writes race with reads. Use separate buffer: gbu is
    // free until gemm writes g... but gemm reads a1 and writes g. Keep a1 in its own slot:
    // (we pass gbu as a1 storage, and g goes to h0b, which is dead after agg1.)

    // g = relu(a1 @ W1 + b1) @ W2 -> h0b (h0 dead after agg1)
    gemm_fused<<<(N_NODES + 63) / 64, 256, 0, stream>>>((const ushort_t*)gbu, W1t, b1,
                                                        W2t, (ushort_t*)h0b);
    // out = relu(segsum(g[src]) + b2)  (fp32 out)
    agg_out<<<N_NODES / 4, 256, 0, stream>>>((const uint2*)h0b, ssrc, off, b2, out);
}

// Round 14
// 201.521 us; speedup vs baseline: 1.2892x; 1.0170x over previous
//
#include <hip/hip_runtime.h>

#define N_NODES 50000
#define N_EDGES 800000
#define CDIM 100
#define HDIM 200
#define ODIM 100

#define PITCH_U 64   // node rows: 128 bf16 = 64 uints = 256 B

typedef __bf16 bf16x8 __attribute__((ext_vector_type(8)));
typedef float f32x4 __attribute__((ext_vector_type(4)));
typedef unsigned short ushort_t;

__device__ __forceinline__ unsigned f2bf(float f) {
    unsigned u = __float_as_uint(f);
    u = (u + 0x7FFFu + ((u >> 16) & 1u)) >> 16;
    return u;  // low 16 bits valid
}
__device__ __forceinline__ float bflo(unsigned u) { return __uint_as_float(u << 16); }
__device__ __forceinline__ float bfhi(unsigned u) { return __uint_as_float(u & 0xFFFF0000u); }

// ---- CSR aggregation core (R11-proven): 1 wave/node, 64 lanes x uint, 8-deep ILP ----
__device__ __forceinline__ float2 agg_core(int n, int lane, const unsigned* __restrict__ hb,
                                           const int* __restrict__ ssrc,
                                           const int* __restrict__ off) {
    int s0 = off[n], s1 = off[n + 1];
    float2 a0 = {0.f, 0.f}, a1 = {0.f, 0.f}, a2 = {0.f, 0.f}, a3 = {0.f, 0.f};
    int j = s0;
    for (; j + 7 < s1; j += 8) {
        int r0 = ssrc[j],     r1 = ssrc[j + 1], r2 = ssrc[j + 2], r3 = ssrc[j + 3];
        int r4 = ssrc[j + 4], r5 = ssrc[j + 5], r6 = ssrc[j + 6], r7 = ssrc[j + 7];
        unsigned u0 = hb[(size_t)r0 * PITCH_U + lane];
        unsigned u1 = hb[(size_t)r1 * PITCH_U + lane];
        unsigned u2 = hb[(size_t)r2 * PITCH_U + lane];
        unsigned u3 = hb[(size_t)r3 * PITCH_U + lane];
        unsigned u4 = hb[(size_t)r4 * PITCH_U + lane];
        unsigned u5 = hb[(size_t)r5 * PITCH_U + lane];
        unsigned u6 = hb[(size_t)r6 * PITCH_U + lane];
        unsigned u7 = hb[(size_t)r7 * PITCH_U + lane];
        a0.x += bflo(u0); a0.y += bfhi(u0);
        a1.x += bflo(u1); a1.y += bfhi(u1);
        a2.x += bflo(u2); a2.y += bfhi(u2);
        a3.x += bflo(u3); a3.y += bfhi(u3);
        a0.x += bflo(u4); a0.y += bfhi(u4);
        a1.x += bflo(u5); a1.y += bfhi(u5);
        a2.x += bflo(u6); a2.y += bfhi(u6);
        a3.x += bflo(u7); a3.y += bfhi(u7);
    }
    for (; j + 3 < s1; j += 4) {
        int r0 = ssrc[j], r1 = ssrc[j + 1], r2 = ssrc[j + 2], r3 = ssrc[j + 3];
        unsigned u0 = hb[(size_t)r0 * PITCH_U + lane];
        unsigned u1 = hb[(size_t)r1 * PITCH_U + lane];
        unsigned u2 = hb[(size_t)r2 * PITCH_U + lane];
        unsigned u3 = hb[(size_t)r3 * PITCH_U + lane];
        a0.x += bflo(u0); a0.y += bfhi(u0);
        a1.x += bflo(u1); a1.y += bfhi(u1);
        a2.x += bflo(u2); a2.y += bfhi(u2);
        a3.x += bflo(u3); a3.y += bfhi(u3);
    }
    {
        int rem = s1 - j;
        if (rem > 0) { unsigned u = hb[(size_t)ssrc[j] * PITCH_U + lane];     a0.x += bflo(u); a0.y += bfhi(u); }
        if (rem > 1) { unsigned u = hb[(size_t)ssrc[j + 1] * PITCH_U + lane]; a1.x += bflo(u); a1.y += bfhi(u); }
        if (rem > 2) { unsigned u = hb[(size_t)ssrc[j + 2] * PITCH_U + lane]; a2.x += bflo(u); a2.y += bfhi(u); }
    }
    return make_float2((a0.x + a1.x) + (a2.x + a3.x), (a0.y + a1.y) + (a2.y + a3.y));
}

// ---------------- fused independent stage: count_rank | gather | weight-prep ----------
// blocks [0,3125): deg histogram + per-edge rank (atomics)
// blocks [3125,9375): h0 = bf16(emb[ids]) into pitch-256B rows (pad cols zeroed)
// blocks [9375,9591): W1t[208][128] <- bf16(W1^T); W2t[112][256] <- bf16(W2^T)

__global__ __launch_bounds__(256) void count_gather_prep(
    const int* __restrict__ edst, int* __restrict__ deg, int* __restrict__ rank,
    const float4* __restrict__ emb, const int* __restrict__ ids, uint2* __restrict__ h0,
    const float* __restrict__ W1, const float* __restrict__ W2,
    ushort_t* __restrict__ W1t, ushort_t* __restrict__ W2t) {
    int b = blockIdx.x;
    if (b < 3125) {
        int e = b * 256 + threadIdx.x;  // 3125*256 == N_EDGES
        rank[e] = atomicAdd(&deg[edst[e]], 1);
    } else if (b < 9375) {
        int i = (b - 3125) * 256 + threadIdx.x;  // i = n*32+q (32 uint2 per row)
        int n = i >> 5, q = i & 31;              // 6250*256 == N*32
        uint2 o = make_uint2(0u, 0u);
        if (q < 25) {
            float4 v = emb[(size_t)ids[n] * 25 + q];
            o.x = f2bf(v.x) | (f2bf(v.y) << 16);
            o.y = f2bf(v.z) | (f2bf(v.w) << 16);
        }
        h0[i] = o;
    } else {
        int i = (b - 9375) * 256 + threadIdx.x;
        if (i < 208 * 128) {
            int n = i >> 7, k = i & 127;
            float v = (n < HDIM && k < CDIM) ? W1[k * HDIM + n] : 0.f;
            W1t[i] = (ushort_t)f2bf(v);
        } else {
            int j = i - 208 * 128;
            if (j < 112 * 256) {
                int n = j >> 8, k = j & 255;
                float v = (n < ODIM && k < HDIM) ? W2[k * ODIM + n] : 0.f;
                W2t[j] = (ushort_t)f2bf(v);
            }
        }
    }
}

__global__ __launch_bounds__(1024) void scan_deg(const int* __restrict__ deg,
                                                 int* __restrict__ off) {
    const int T = 1024;
    const int PER = 52;  // 13 int4s; 962 threads cover 50000
    int t = threadIdx.x;
    int start = t * PER;
    const int4* deg4 = (const int4*)deg;

    int sum = 0;
    if (start + PER <= N_NODES) {
#pragma unroll
        for (int q = 0; q < PER / 4; ++q) {
            int4 v = deg4[start / 4 + q];
            sum += v.x + v.y + v.z + v.w;
        }
    } else {
        for (int i = start; i < N_NODES; ++i) sum += deg[i];
    }

    __shared__ int ls[T];
    ls[t] = sum;
    __syncthreads();
    for (int o = 1; o < T; o <<= 1) {
        int v = (t >= o) ? ls[t - o] : 0;
        __syncthreads();
        ls[t] += v;
        __syncthreads();
    }
    int run = (t == 0) ? 0 : ls[t - 1];

    if (start + PER <= N_NODES) {
        int4* off4 = (int4*)off;
#pragma unroll
        for (int q = 0; q < PER / 4; ++q) {
            int4 v = deg4[start / 4 + q];
            int4 o;
            o.x = run;
            o.y = o.x + v.x;
            o.z = o.y + v.y;
            o.w = o.z + v.z;
            run = o.w + v.w;
            off4[start / 4 + q] = o;
        }
    } else if (start <= N_NODES) {
        for (int i = start; i < N_NODES; ++i) {
            off[i] = run;
            run += deg[i];
        }
        off[N_NODES] = run;
    }
}

// ---------------- atomic-free scatter: slot = off[dst] + rank ----------------

__global__ __launch_bounds__(256) void scatter(const int* __restrict__ esrc,
                                               const int* __restrict__ edst,
                                               const int* __restrict__ off,
                                               const int* __restrict__ rank,
                                               int* __restrict__ ssrc) {
    int e = blockIdx.x * 256 + threadIdx.x;
    if (e < N_EDGES) {
        int p = off[edst[e]] + rank[e];
        ssrc[p] = esrc[e];
    }
}

// ---------------- agg1: a1 = segsum(h0[src]) -> bf16 pitch-256B (R11-proven) --------

__global__ __launch_bounds__(256) void agg1(const unsigned* __restrict__ hb,
                                            const int* __restrict__ ssrc,
                                            const int* __restrict__ off,
                                            unsigned* __restrict__ outb) {
    int wave = threadIdx.x >> 6;
    int lane = threadIdx.x & 63;
    int n = blockIdx.x * 4 + wave;
    if (n >= N_NODES) return;
    float2 r = agg_core(n, lane, hb, ssrc, off);
    outb[(size_t)n * PITCH_U + lane] = f2bf(r.x) | (f2bf(r.y) << 16);
}

// ---------------- fused MLP: g = relu(A @ W1t^T + b1) @ W2t^T (R11-proven) --------

__global__ __launch_bounds__(256) void gemm_fused(const ushort_t* __restrict__ Ab,
                                                  const ushort_t* __restrict__ W1t,
                                                  const float* __restrict__ b1,
                                                  const ushort_t* __restrict__ W2t,
                                                  ushort_t* __restrict__ gb) {
    const int P2 = 264;  // H1s row pitch (bf16): 200 data + 56 zero + 8 slack
    __shared__ alignas(16) ushort_t H1s[64 * P2];  // 33.8 KB

    int tid = threadIdx.x, lane = tid & 63, w = tid >> 6;
    int rl = lane & 15, kg = lane >> 4;
    int row0 = blockIdx.x * 64;

    size_t abase = ((size_t)(row0 + w * 16 + rl)) * 128;
    f32x4 acc1[13];
#pragma unroll
    for (int t = 0; t < 13; ++t) acc1[t] = (f32x4){0.f, 0.f, 0.f, 0.f};
#pragma unroll
    for (int k2 = 0; k2 < 4; ++k2) {
        bf16x8 a = *reinterpret_cast<const bf16x8*>(&Ab[abase + k2 * 32 + kg * 8]);
#pragma unroll
        for (int t = 0; t < 13; ++t) {
            bf16x8 b = *reinterpret_cast<const bf16x8*>(&W1t[(t * 16 + rl) * 128 + k2 * 32 + kg * 8]);
            acc1[t] = __builtin_amdgcn_mfma_f32_16x16x32_bf16(a, b, acc1[t], 0, 0, 0);
        }
    }
    // zero pad cols 200..263
    for (int idx = tid; idx < 64 * 32; idx += 256) {
        int r = idx >> 5, c = idx & 31;
        ((unsigned*)&H1s[r * P2 + 200])[c] = 0;
    }
    // h1 = relu(acc1 + b1) -> bf16 LDS tile (D layout: col=lane&15, row=(lane>>4)*4+i)
#pragma unroll
    for (int t = 0; t < 13; ++t) {
        int col = t * 16 + rl;
        if (col < HDIM) {
            float bv = b1[col];
#pragma unroll
            for (int i = 0; i < 4; ++i) {
                int r = w * 16 + kg * 4 + i;
                H1s[r * P2 + col] = (ushort_t)f2bf(fmaxf(acc1[t][i] + bv, 0.f));
            }
        }
    }
    __syncthreads();

    f32x4 acc2[7];
#pragma unroll
    for (int t = 0; t < 7; ++t) acc2[t] = (f32x4){0.f, 0.f, 0.f, 0.f};
#pragma unroll
    for (int k2 = 0; k2 < 8; ++k2) {
        bf16x8 a = *reinterpret_cast<const bf16x8*>(&H1s[(w * 16 + rl) * P2 + k2 * 32 + kg * 8]);
#pragma unroll
        for (int t = 0; t < 7; ++t) {
            bf16x8 b = *reinterpret_cast<const bf16x8*>(&W2t[(t * 16 + rl) * 256 + k2 * 32 + kg * 8]);
            acc2[t] = __builtin_amdgcn_mfma_f32_16x16x32_bf16(a, b, acc2[t], 0, 0, 0);
        }
    }

#pragma unroll
    for (int t = 0; t < 7; ++t) {
        int col = t * 16 + rl;
#pragma unroll
        for (int i = 0; i < 4; ++i) {
            int row = row0 + w * 16 + kg * 4 + i;
            if (row < N_NODES) {
                float v = (col < ODIM) ? acc2[t][i] : 0.f;
                gb[(size_t)row * 128 + col] = (ushort_t)f2bf(v);
            }
        }
    }
    unsigned* gbu = (unsigned*)gb;
    for (int idx = tid; idx < 64 * 8; idx += 256) {
        int r = idx >> 3, c = idx & 7;
        int row = row0 + r;
        if (row < N_NODES) gbu[(size_t)row * PITCH_U + 56 + c] = 0;
    }
}

// ---------------- final aggregation: out = relu(segsum(g[src]) + b2) ----------------

__global__ __launch_bounds__(256) void agg_out(const unsigned* __restrict__ hb,
                                               const int* __restrict__ ssrc,
                                               const int* __restrict__ off,
                                               const float* __restrict__ bias,
                                               float2* __restrict__ outf) {
    int wave = threadIdx.x >> 6;
    int lane = threadIdx.x & 63;
    int n = blockIdx.x * 4 + wave;
    if (n >= N_NODES) return;
    float2 r = agg_core(n, lane, hb, ssrc, off);
    if (lane < 50) {
        float rx = fmaxf(r.x + bias[2 * lane], 0.f);
        float ry = fmaxf(r.y + bias[2 * lane + 1], 0.f);
        outf[(size_t)n * 50 + lane] = make_float2(rx, ry);
    }
}

// ---------------- launch ----------------

extern "C" void kernel_launch(void* const* d_in, const int* in_sizes, int n_in,
                              void* d_out, int out_size, void* d_ws, size_t ws_size,
                              hipStream_t stream) {
    const float4* emb = (const float4*)d_in[0];
    const float* W1  = (const float*)d_in[1];
    const float* b1  = (const float*)d_in[2];
    const float* W2  = (const float*)d_in[3];
    const float* b2  = (const float*)d_in[4];
    const int* ids   = (const int*)d_in[5];
    const int* esrc  = (const int*)d_in[6];
    const int* edst  = (const int*)d_in[7];
    float2* out = (float2*)d_out;

    // workspace layout (~33 MB)
    unsigned* h0b = (unsigned*)d_ws;                    // [N][64] uints (bf16 pairs)
    unsigned* a1b = h0b + (size_t)N_NODES * PITCH_U;    // [N][64] uints (a1, then g reuses h0b)
    ushort_t* W1t = (ushort_t*)(a1b + (size_t)N_NODES * PITCH_U);  // [208][128]
    ushort_t* W2t = W1t + 208 * 128;                    // [112][256]
    int* deg   = (int*)(W2t + 112 * 256);
    int* off   = deg + N_NODES;                         // N+1
    int* rank  = off + (N_NODES + 1);                   // 800K
    int* ssrc  = rank + N_EDGES;                        // 800K

    hipMemsetAsync(deg, 0, N_NODES * sizeof(int), stream);

    // count_rank | h0 gather | weight prep (independent) in one launch
    count_gather_prep<<<9591, 256, 0, stream>>>(edst, deg, rank,
                                                emb, ids, (uint2*)h0b,
                                                W1, W2, W1t, W2t);
    scan_deg<<<1, 1024, 0, stream>>>(deg, off);
    // atomic-free scatter
    scatter<<<3125, 256, 0, stream>>>(esrc, edst, off, rank, ssrc);

    // agg1 = segsum(h0[src]) -> a1b (bf16 pitch-256B)
    agg1<<<N_NODES / 4, 256, 0, stream>>>(h0b, ssrc, off, a1b);
    // g = relu(a1 @ W1 + b1) @ W2 -> h0b (h0 dead after agg1)
    gemm_fused<<<(N_NODES + 63) / 64, 256, 0, stream>>>((const ushort_t*)a1b, W1t, b1,
                                                        W2t, (ushort_t*)h0b);
    // out = relu(segsum(g[src]) + b2)  (fp32 out)
    agg_out<<<N_NODES / 4, 256, 0, stream>>>(h0b, ssrc, off, b2, out);
}